// Round 3
// baseline (127.461 us; speedup 1.0000x reference)
//
#include <hip/hip_runtime.h>
#include <hip/hip_fp16.h>

typedef __attribute__((ext_vector_type(4))) float f32x4;
typedef __attribute__((ext_vector_type(8))) _Float16 f16x8;
typedef __attribute__((ext_vector_type(4))) unsigned int u32x4;

// float -> fp16 bits, round-nearest-even
__device__ __forceinline__ unsigned short f2h(float f) {
  __half h = __float2half_rn(f);
  unsigned short u;
  __builtin_memcpy(&u, &h, 2);
  return u;
}
// dword <-> __half2 helpers (ext_vector elements can't be addressed directly)
__device__ __forceinline__ __half2 h2_of(unsigned int u) {
  __half2 h;
  __builtin_memcpy(&h, &u, 4);
  return h;
}
__device__ __forceinline__ unsigned int u_of(__half2 h) {
  unsigned int u;
  __builtin_memcpy(&u, &h, 4);
  return u;
}

// ---------------------------------------------------------------------------
// Prep kernel, round 16: weights repack (blocks 0..71, verified R14) PLUS
// full sampling-table precompute (blocks 72..1223).
// Table entry (b,ho,tap,wo) -> int4 {laT|aX|oowT, laB|aY|oowB, topWts, botWts}
// layout tab[((b*64+ho)*9 + tap)*64 + wo]; laT/laB are LDS byte offsets into
// deform's 8-row window for the block owning (b, ho&~1). Moving this table to
// global (L2-resident, coalesced dwordx4 reads, prefetched a tap ahead)
// removes 288 b128 reads/block plus the table-gen pass from deform's
// LDS-bound main loop.
// ---------------------------------------------------------------------------
__global__ __launch_bounds__(256) void prep_kernel(const float* __restrict__ w,
                                                   const float* __restrict__ off,
                                                   unsigned short* __restrict__ wf,
                                                   int4* __restrict__ tab) {
  if (blockIdx.x < 72) {
    int tid = blockIdx.x * 256 + threadIdx.x;   // 0..18431
    int l  = tid & 63;
    int mt = (tid >> 6) & 7;
    int ch = tid >> 9;                          // 0..35
    int cc = ch / 9, tap = ch - cc * 9;
    int co = mt * 16 + (l & 15);
    int cb = cc * 32 + (l >> 4) * 8;
    unsigned int r[8];
#pragma unroll
    for (int j = 0; j < 8; ++j)
      r[j] = f2h(w[(co * 128 + cb + j) * 9 + tap]);
    u32x4 pk;
    pk.x = r[0] | (r[1] << 16);
    pk.y = r[2] | (r[3] << 16);
    pk.z = r[4] | (r[5] << 16);
    pk.w = r[6] | (r[7] << 16);
    *reinterpret_cast<u32x4*>(wf + (size_t)tid * 8) = pk;
  } else {
    int t = (blockIdx.x - 72) * 256 + threadIdx.x;   // 0..294911
    int wo  = t & 63;
    int q   = t >> 6;            // [b:3][ho:6][tap:?] -> q = (b*64+ho)*9 + tap
    int tap = q % 9;
    int rest = q / 9;            // b*64 + ho
    int ho  = rest & 63;
    int b   = rest >> 6;
    int ho0 = ho & ~1;
    int r0  = min(max(ho0 - 3, 0), 56);

    float dy = off[((b * 18 + 2 * tap)     * 64 + ho) * 64 + wo];
    float dx = off[((b * 18 + 2 * tap + 1) * 64 + ho) * 64 + wo];
    float py = (float)(ho + (tap / 3) - 1) + dy;
    float px = (float)(wo + (tap % 3) - 1) + dx;
    float fy = floorf(py), fx = floorf(px);
    int y0 = (int)fy, x0 = (int)fx;
    float wy = py - fy, wx = px - fx;
    float wt = (y0 >= 0 && y0 < 64) ? (1.f - wy) : 0.f;
    float wb = (y0 + 1 >= 0 && y0 + 1 < 64) ? wy : 0.f;
    int y0c = min(max(y0, 0), 63), y1c = min(max(y0 + 1, 0), 63);
    int bx; float wl, wr;
    if (x0 >= 0 && x0 <= 62)      { bx = x0; wl = 1.f - wx; wr = wx;       }
    else if (x0 == -1)            { bx = 0;  wl = wx;       wr = 0.f;      }
    else if (x0 == 63)            { bx = 62; wl = 0.f;      wr = 1.f - wx; }
    else                          { bx = 0;  wl = 0.f;      wr = 0.f;      }
    int aX = y0c * 64 + bx, aY = y1c * 64 + bx;
    int twr = y0c - r0, bwr = y1c - r0;
    int tin = ((unsigned)twr < 8u) ? 1 : 0;
    int bin = ((unsigned)bwr < 8u) ? 1 : 0;
    int laT0 = (tin ? twr : 0) * 17408 + bx * 272;
    int laB0 = (bin ? bwr : 0) * 17408 + bx * 272;
    int4 pw;
    pw.x = laT0 | (aX << 18) | (tin ? 0 : (int)0x80000000);
    pw.y = laB0 | (aY << 18) | (bin ? 0 : (int)0x80000000);
    pw.z = (int)u_of(__floats2half2_rn(wt * wl, wt * wr));
    pw.w = (int)u_of(__floats2half2_rn(wb * wl, wb * wr));
    tab[t] = pw;
  }
}

// ---------------------------------------------------------------------------
// Main kernel, round 16: R15 + table-to-global + balanced butterfly epilogue.
// (1) Sampling table read from global (dwordx4, 256 B/16-lane coalesced,
//     L2-hot, double-buffered a full tap ahead) -> LDS pipe now carries only
//     window reads + staging + reduce (was +3.5k cyc of table b128s).
// (2) Epilogue: 2-level balanced butterfly (ks^1 then ks^2). Each wave ends
//     with a fully-reduced 2-mt quarter; reduction order ((k0+k1)+(k2+k3))
//     is bitwise-identical to the old tree. LDS regions: per-wave w*4352
//     floats, pos-stride 68 (2-way bank aliasing = free), exactly filling
//     sWin. All 8 waves then store straight from registers (32 dwords each,
//     4x64B segments/instr) -> old LDS-transpose epilogue (2.3k cyc) gone.
// Everything else verified R12-R15: fused fp32->fp16 window staging (XCD-L2
// resident, b == XCD id), 8-row window p-stride 272, rolling 3-slot ISSUE/
// INTERP pipeline, fp16 v_pk_fma interp -> mfma_f32_16x16x32_f16.
// LDS: sWin 139264 B only (1 block/CU, 8 waves).
// ---------------------------------------------------------------------------
__global__ __launch_bounds__(512, 1) void deform_kernel(const float* __restrict__ x,
                                                        const int4* __restrict__ tab,
                                                        const unsigned short* __restrict__ wf,
                                                        float* __restrict__ out) {
  // window: [r][p][c] bytes, p-stride 272 (16B pad), r-stride 64*272=17408
  __shared__ __align__(16) unsigned char sWin[8 * 17408];   // 139264 B

  const int tid = threadIdx.x;
  const int bid = blockIdx.x;
  const int b   = bid & 7;             // XCD-affine batch
  const int ho0 = (bid >> 3) * 2;      // first of the 2 output rows
  const int r0  = min(max(ho0 - 3, 0), 56);   // window base row

  const int l   = tid & 63;
  const int w   = tid >> 6;       // wave id 0..7
  const int ks  = w & 3;          // channel slab
  const int row = w >> 2;         // output row (ho0 + row)
  const int ln  = l & 15;
  const int kg  = l >> 4;         // k-group (8 consecutive channels)
  const int koff = ks * 64 + kg * 16;   // lane's channel byte offset in record
  const int ho  = ho0 + row;

  // global table base for this wave's row: entries [tap*64 + pg*16 + ln]
  const int4* tabp = tab + (size_t)((b * 64 + ho) * 9) * 64 + ln;

  // preload tap 0's table entries (global, L2-hot; no LDS dependency)
  int4 tbc[4];
#pragma unroll
  for (int pg = 0; pg < 4; ++pg) tbc[pg] = tabp[pg * 16];

  // --- stage window rows r0..r0+7 from x (fp32 NCHW -> fp16 window) ---
  {
    const float* xb = x + ((size_t)b << 19) + ((size_t)r0 << 6);
#pragma unroll
    for (int it = 0; it < 16; ++it) {
      int idx = it * 512 + tid;        // [cg:4][r:3][p:6], 0..8191
      int p  = idx & 63;               // lane = p -> coalesced reads
      int r  = (idx >> 6) & 7;
      int cg = idx >> 9;
      const float* xp = xb + (((size_t)cg) << 15) + (r << 6) + p;
      unsigned int q[8];
#pragma unroll
      for (int j = 0; j < 8; ++j) q[j] = f2h(xp[(size_t)j << 12]);
      u32x4 pk;
      pk.x = q[0] | (q[1] << 16);
      pk.y = q[2] | (q[3] << 16);
      pk.z = q[4] | (q[5] << 16);
      pk.w = q[6] | (q[7] << 16);
      *reinterpret_cast<u32x4*>(&sWin[r * 17408 + p * 272 + cg * 16]) = pk;
    }
  }
  __syncthreads();

  // per-lane fp32 base for the rare out-of-window fallback: channels
  // ks*32+kg*8 .. +7, planes 4096 floats apart
  const float* xfb = x + ((size_t)b << 19) + (((size_t)(ks * 32 + kg * 8)) << 12);
  const unsigned short* wfb = wf + (size_t)l * 8;

  f32x4 acc[4][8] = {};   // [pos-group][m-tile] -> AGPRs

#define ISSUE(S, PG) {                                                         \
    const int4 tb = tbc[PG];                                                   \
    const int laT = (tb.x & 0x3FFFF) + koff;                                   \
    __builtin_memcpy(&T0[S], &sWin[laT],       16);                            \
    __builtin_memcpy(&T1[S], &sWin[laT + 272], 16);                            \
    const int laB = (tb.y & 0x3FFFF) + koff;                                   \
    __builtin_memcpy(&B0[S], &sWin[laB],       16);                            \
    __builtin_memcpy(&B1[S], &sWin[laB + 272], 16);                            \
    if (tb.x < 0) {   /* rare: top sample row outside window -> global fp32 */ \
      const float* p0 = xfb + ((tb.x >> 18) & 4095);                           \
      u32x4 q0, q1;                                                            \
      _Pragma("unroll") for (int d = 0; d < 4; ++d) {                          \
        unsigned int a0 = f2h(p0[(size_t)(2 * d)     << 12]);                  \
        unsigned int a1 = f2h(p0[(size_t)(2 * d + 1) << 12]);                  \
        q0[d] = a0 | (a1 << 16);                                               \
        unsigned int c0 = f2h(p0[((size_t)(2 * d)     << 12) + 1]);            \
        unsigned int c1 = f2h(p0[((size_t)(2 * d + 1) << 12) + 1]);            \
        q1[d] = c0 | (c1 << 16);                                               \
      }                                                                        \
      T0[S] = q0; T1[S] = q1;                                                  \
    }                                                                          \
    if (tb.y < 0) {   /* rare: bottom sample row outside window */             \
      const float* p1 = xfb + ((tb.y >> 18) & 4095);                           \
      u32x4 q0, q1;                                                            \
      _Pragma("unroll") for (int d = 0; d < 4; ++d) {                          \
        unsigned int a0 = f2h(p1[(size_t)(2 * d)     << 12]);                  \
        unsigned int a1 = f2h(p1[(size_t)(2 * d + 1) << 12]);                  \
        q0[d] = a0 | (a1 << 16);                                               \
        unsigned int c0 = f2h(p1[((size_t)(2 * d)     << 12) + 1]);            \
        unsigned int c1 = f2h(p1[((size_t)(2 * d + 1) << 12) + 1]);            \
        q1[d] = c0 | (c1 << 16);                                               \
      }                                                                        \
      B0[S] = q0; B1[S] = q1;                                                  \
    }                                                                          \
  }

#define INTERP(S, PG) {                                                        \
    const __half2 wtl = __half2half2(__low2half(h2_of((unsigned)tbc[PG].z)));  \
    const __half2 wtr = __half2half2(__high2half(h2_of((unsigned)tbc[PG].z))); \
    const __half2 wbl = __half2half2(__low2half(h2_of((unsigned)tbc[PG].w)));  \
    const __half2 wbr = __half2half2(__high2half(h2_of((unsigned)tbc[PG].w))); \
    u32x4 pk;                                                                  \
    _Pragma("unroll") for (int d = 0; d < 4; ++d) {                            \
      __half2 s = __hmul2(wtl, h2_of(T0[S][d]));                               \
      s = __hfma2(wtr, h2_of(T1[S][d]), s);                                    \
      s = __hfma2(wbl, h2_of(B0[S][d]), s);                                    \
      s = __hfma2(wbr, h2_of(B1[S][d]), s);                                    \
      pk[d] = u_of(s);                                                         \
    }                                                                          \
    f16x8 bfrag;                                                               \
    __builtin_memcpy(&bfrag, &pk, 16);                                         \
    _Pragma("unroll") for (int mt = 0; mt < 8; ++mt)                           \
      acc[PG][mt] = __builtin_amdgcn_mfma_f32_16x16x32_f16(A[mt], bfrag,       \
                                                           acc[PG][mt], 0, 0, 0); \
  }

  for (int tap = 0; tap < 9; ++tap) {
    // prefetch next tap's table entries (global, hidden under this tap's body)
    int4 tbn[4];
    if (tap < 8) {
#pragma unroll
      for (int pg = 0; pg < 4; ++pg)
        tbn[pg] = tabp[(tap + 1) * 64 + pg * 16];
    }

    // A-fragments: all 8 m-tiles (full Cout per wave), global L2-hot
    f16x8 A[8];
    const unsigned short* wp = wfb + (size_t)((ks * 9 + tap) * 8) * 512;
#pragma unroll
    for (int mt = 0; mt < 8; ++mt)
      A[mt] = *reinterpret_cast<const f16x8*>(wp + (size_t)mt * 512);

    // rolling 3-slot T/B window: addresses come straight from tbc registers
    u32x4 T0[3], T1[3], B0[3], B1[3];
    ISSUE(0, 0)
    ISSUE(1, 1)
    ISSUE(2, 2)
    INTERP(0, 0)
    ISSUE(0, 3)
    INTERP(1, 1)
    INTERP(2, 2)
    INTERP(0, 3)

#pragma unroll
    for (int pg = 0; pg < 4; ++pg) tbc[pg] = tbn[pg];
  }
#undef ISSUE
#undef INTERP

  // ---- epilogue: 2-level balanced butterfly reduce, then direct stores ----
  // Per-wave LDS region: w*4352 floats, addr = (pg*16+ln)*68 + slot*16 + kg*4
  // (stride 68 -> 2-way bank aliasing, free). Level 1 pairs ks^1 (exchange
  // mt halves), level 2 pairs ks^2 (exchange mt pairs). Final: wave holds
  // mt pair {keep2, keep2+1} summed ((k0+k1)+(k2+k3)) — bitwise-identical
  // association to the old sequential tree.
  {
    float* sF = reinterpret_cast<float*>(sWin);
    const int rbase = w * 4352;
    const int pbase1 = (w ^ 1) * 4352;
    const int pbase2 = (w ^ 2) * 4352;
    const int sendB  = (ks & 1) ? 0 : 4;   // L1: ks0,ks2 send mt4-7
    const int keepB  = 4 - sendB;
    const int send2B = keepB + ((ks >> 1) ? 0 : 2);
    const int keep2B = keepB + ((ks >> 1) ? 2 : 0);

    __syncthreads();   // window reads done; safe to overwrite sWin
#pragma unroll
    for (int pg = 0; pg < 4; ++pg)
#pragma unroll
      for (int mtL = 0; mtL < 4; ++mtL)
        *reinterpret_cast<f32x4*>(&sF[rbase + (pg * 16 + ln) * 68 + mtL * 16 + kg * 4]) = acc[pg][sendB + mtL];
    __syncthreads();
#pragma unroll
    for (int pg = 0; pg < 4; ++pg)
#pragma unroll
      for (int mtL = 0; mtL < 4; ++mtL) {
        f32x4 v = *reinterpret_cast<const f32x4*>(&sF[pbase1 + (pg * 16 + ln) * 68 + mtL * 16 + kg * 4]);
        acc[pg][keepB + mtL] += v;
      }
    __syncthreads();
#pragma unroll
    for (int pg = 0; pg < 4; ++pg)
#pragma unroll
      for (int mtL = 0; mtL < 2; ++mtL)
        *reinterpret_cast<f32x4*>(&sF[rbase + (pg * 16 + ln) * 68 + mtL * 16 + kg * 4]) = acc[pg][send2B + mtL];
    __syncthreads();
#pragma unroll
    for (int pg = 0; pg < 4; ++pg)
#pragma unroll
      for (int mtL = 0; mtL < 2; ++mtL) {
        f32x4 v = *reinterpret_cast<const f32x4*>(&sF[pbase2 + (pg * 16 + ln) * 68 + mtL * 16 + kg * 4]);
        acc[pg][keep2B + mtL] += v;
      }

    // direct stores: wave's final quarter = mt {keep2B, keep2B+1}
    // out[b][co][ho][wo], co = mt*16 + kg*4 + rg, wo = pg*16 + ln
    float* ob = out + (((size_t)b * 128) * 64 + ho) * 64;
#pragma unroll
    for (int pg = 0; pg < 4; ++pg)
#pragma unroll
      for (int mtL = 0; mtL < 2; ++mtL) {
        const int mt = keep2B + mtL;
#pragma unroll
        for (int rg = 0; rg < 4; ++rg) {
          const int co = mt * 16 + kg * 4 + rg;
          ob[(size_t)co * 4096 + pg * 16 + ln] = acc[pg][mt][rg];
        }
      }
  }
}

extern "C" void kernel_launch(void* const* d_in, const int* in_sizes, int n_in,
                              void* d_out, int out_size, void* d_ws, size_t ws_size,
                              hipStream_t stream) {
  (void)in_sizes; (void)n_in; (void)out_size; (void)ws_size;
  const float* x   = (const float*)d_in[0];
  const float* off = (const float*)d_in[1];
  const float* w   = (const float*)d_in[2];
  float* out = (float*)d_out;
  unsigned short* wf = (unsigned short*)d_ws;                    // 294912 B
  int4* tab = (int4*)((char*)d_ws + 294912);                     // 4718592 B

  prep_kernel<<<1224, 256, 0, stream>>>(w, off, wf, tab);
  deform_kernel<<<256, 512, 0, stream>>>(x, tab, wf, out);
}

// Round 4
// 99.601 us; speedup vs baseline: 1.2797x; 1.2797x over previous
//
#include <hip/hip_runtime.h>
#include <hip/hip_fp16.h>

typedef __attribute__((ext_vector_type(4))) float f32x4;
typedef __attribute__((ext_vector_type(8))) _Float16 f16x8;
typedef __attribute__((ext_vector_type(4))) unsigned int u32x4;

// float -> fp16 bits, round-nearest-even
__device__ __forceinline__ unsigned short f2h(float f) {
  __half h = __float2half_rn(f);
  unsigned short u;
  __builtin_memcpy(&u, &h, 2);
  return u;
}
// dword <-> __half2 helpers (ext_vector elements can't be addressed directly)
__device__ __forceinline__ __half2 h2_of(unsigned int u) {
  __half2 h;
  __builtin_memcpy(&h, &u, 4);
  return h;
}
__device__ __forceinline__ unsigned int u_of(__half2 h) {
  unsigned int u;
  __builtin_memcpy(&u, &h, 4);
  return u;
}

// ---------------------------------------------------------------------------
// Prep kernel (verified R16): weights repack (blocks 0..71) + sampling-table
// precompute (blocks 72..1223).
// Table entry (b,ho,tap,wo) -> int4 {laT|aX|oowT, laB|aY|oowB, topWts, botWts}
// layout tab[((b*64+ho)*9 + tap)*64 + wo]; laT/laB are LDS byte offsets into
// deform's 8-row window for the block owning (b, ho&~1).
// ---------------------------------------------------------------------------
__global__ __launch_bounds__(256) void prep_kernel(const float* __restrict__ w,
                                                   const float* __restrict__ off,
                                                   unsigned short* __restrict__ wf,
                                                   int4* __restrict__ tab) {
  if (blockIdx.x < 72) {
    int tid = blockIdx.x * 256 + threadIdx.x;   // 0..18431
    int l  = tid & 63;
    int mt = (tid >> 6) & 7;
    int ch = tid >> 9;                          // 0..35
    int cc = ch / 9, tap = ch - cc * 9;
    int co = mt * 16 + (l & 15);
    int cb = cc * 32 + (l >> 4) * 8;
    unsigned int r[8];
#pragma unroll
    for (int j = 0; j < 8; ++j)
      r[j] = f2h(w[(co * 128 + cb + j) * 9 + tap]);
    u32x4 pk;
    pk.x = r[0] | (r[1] << 16);
    pk.y = r[2] | (r[3] << 16);
    pk.z = r[4] | (r[5] << 16);
    pk.w = r[6] | (r[7] << 16);
    *reinterpret_cast<u32x4*>(wf + (size_t)tid * 8) = pk;
  } else {
    int t = (blockIdx.x - 72) * 256 + threadIdx.x;   // 0..294911
    int wo  = t & 63;
    int q   = t >> 6;            // q = (b*64+ho)*9 + tap
    int tap = q % 9;
    int rest = q / 9;            // b*64 + ho
    int ho  = rest & 63;
    int b   = rest >> 6;
    int ho0 = ho & ~1;
    int r0  = min(max(ho0 - 3, 0), 56);

    float dy = off[((b * 18 + 2 * tap)     * 64 + ho) * 64 + wo];
    float dx = off[((b * 18 + 2 * tap + 1) * 64 + ho) * 64 + wo];
    float py = (float)(ho + (tap / 3) - 1) + dy;
    float px = (float)(wo + (tap % 3) - 1) + dx;
    float fy = floorf(py), fx = floorf(px);
    int y0 = (int)fy, x0 = (int)fx;
    float wy = py - fy, wx = px - fx;
    float wt = (y0 >= 0 && y0 < 64) ? (1.f - wy) : 0.f;
    float wb = (y0 + 1 >= 0 && y0 + 1 < 64) ? wy : 0.f;
    int y0c = min(max(y0, 0), 63), y1c = min(max(y0 + 1, 0), 63);
    int bx; float wl, wr;
    if (x0 >= 0 && x0 <= 62)      { bx = x0; wl = 1.f - wx; wr = wx;       }
    else if (x0 == -1)            { bx = 0;  wl = wx;       wr = 0.f;      }
    else if (x0 == 63)            { bx = 62; wl = 0.f;      wr = 1.f - wx; }
    else                          { bx = 0;  wl = 0.f;      wr = 0.f;      }
    int aX = y0c * 64 + bx, aY = y1c * 64 + bx;
    int twr = y0c - r0, bwr = y1c - r0;
    int tin = ((unsigned)twr < 8u) ? 1 : 0;
    int bin = ((unsigned)bwr < 8u) ? 1 : 0;
    int laT0 = (tin ? twr : 0) * 17408 + bx * 272;
    int laB0 = (bin ? bwr : 0) * 17408 + bx * 272;
    int4 pw;
    pw.x = laT0 | (aX << 18) | (tin ? 0 : (int)0x80000000);
    pw.y = laB0 | (aY << 18) | (bin ? 0 : (int)0x80000000);
    pw.z = (int)u_of(__floats2half2_rn(wt * wl, wt * wr));
    pw.w = (int)u_of(__floats2half2_rn(wb * wl, wb * wr));
    tab[t] = pw;
  }
}

// ---------------------------------------------------------------------------
// Main kernel, round 17: R16's global-table main loop + R15's VERIFIED
// epilogue (5-barrier pairwise tree + LDS transpose + ks==0 dwordx4 stores).
// R16 post-mortem: the direct scalar stores caused 11x HBM write
// amplification (WRITE_SIZE 189 MB vs 16.8 MB output; 64 B partial-line
// segments at 16 KB stride thrashing per-XCD L2) -> deform went memory-bound
// at 259 MB/dispatch. The transpose epilogue stores 256 B-contiguous
// segments (1 KB per instruction) and is restored verbatim.
// Kept from R16: sampling table in global (dwordx4, L2-hot, prefetched a
// full tap ahead) -> LDS pipe carries only window reads + staging + reduce.
// Everything else verified R12-R15: fused fp32->fp16 window staging (XCD-L2
// resident, b == XCD id), 8-row window p-stride 272, rolling 3-slot ISSUE/
// INTERP pipeline, fp16 v_pk_fma interp -> mfma_f32_16x16x32_f16.
// LDS: sWin 139264 B only (1 block/CU, 8 waves).
// LDS float map (34816 floats): transpose rgn [row*8704, +8704),
// regB [0,16896), regA [17408, 34304).
// ---------------------------------------------------------------------------
__global__ __launch_bounds__(512, 1) void deform_kernel(const float* __restrict__ x,
                                                        const int4* __restrict__ tab,
                                                        const unsigned short* __restrict__ wf,
                                                        float* __restrict__ out) {
  // window: [r][p][c] bytes, p-stride 272 (16B pad), r-stride 64*272=17408
  __shared__ __align__(16) unsigned char sWin[8 * 17408];   // 139264 B

  const int tid = threadIdx.x;
  const int bid = blockIdx.x;
  const int b   = bid & 7;             // XCD-affine batch
  const int ho0 = (bid >> 3) * 2;      // first of the 2 output rows
  const int r0  = min(max(ho0 - 3, 0), 56);   // window base row

  const int l   = tid & 63;
  const int w   = tid >> 6;       // wave id 0..7
  const int ks  = w & 3;          // channel slab
  const int row = w >> 2;         // output row (ho0 + row)
  const int ln  = l & 15;
  const int kg  = l >> 4;         // k-group (8 consecutive channels)
  const int koff = ks * 64 + kg * 16;   // lane's channel byte offset in record
  const int ho  = ho0 + row;

  // global table base for this wave's row: entries [tap*64 + pg*16 + ln]
  const int4* tabp = tab + (size_t)((b * 64 + ho) * 9) * 64 + ln;

  // preload tap 0's table entries (global, L2-hot; no LDS dependency)
  int4 tbc[4];
#pragma unroll
  for (int pg = 0; pg < 4; ++pg) tbc[pg] = tabp[pg * 16];

  // --- stage window rows r0..r0+7 from x (fp32 NCHW -> fp16 window) ---
  {
    const float* xb = x + ((size_t)b << 19) + ((size_t)r0 << 6);
#pragma unroll
    for (int it = 0; it < 16; ++it) {
      int idx = it * 512 + tid;        // [cg:4][r:3][p:6], 0..8191
      int p  = idx & 63;               // lane = p -> coalesced reads
      int r  = (idx >> 6) & 7;
      int cg = idx >> 9;
      const float* xp = xb + (((size_t)cg) << 15) + (r << 6) + p;
      unsigned int q[8];
#pragma unroll
      for (int j = 0; j < 8; ++j) q[j] = f2h(xp[(size_t)j << 12]);
      u32x4 pk;
      pk.x = q[0] | (q[1] << 16);
      pk.y = q[2] | (q[3] << 16);
      pk.z = q[4] | (q[5] << 16);
      pk.w = q[6] | (q[7] << 16);
      *reinterpret_cast<u32x4*>(&sWin[r * 17408 + p * 272 + cg * 16]) = pk;
    }
  }
  __syncthreads();

  // per-lane fp32 base for the rare out-of-window fallback: channels
  // ks*32+kg*8 .. +7, planes 4096 floats apart
  const float* xfb = x + ((size_t)b << 19) + (((size_t)(ks * 32 + kg * 8)) << 12);
  const unsigned short* wfb = wf + (size_t)l * 8;

  f32x4 acc[4][8] = {};   // [pos-group][m-tile] -> AGPRs

#define ISSUE(S, PG) {                                                         \
    const int4 tb = tbc[PG];                                                   \
    const int laT = (tb.x & 0x3FFFF) + koff;                                   \
    __builtin_memcpy(&T0[S], &sWin[laT],       16);                            \
    __builtin_memcpy(&T1[S], &sWin[laT + 272], 16);                            \
    const int laB = (tb.y & 0x3FFFF) + koff;                                   \
    __builtin_memcpy(&B0[S], &sWin[laB],       16);                            \
    __builtin_memcpy(&B1[S], &sWin[laB + 272], 16);                            \
    if (tb.x < 0) {   /* rare: top sample row outside window -> global fp32 */ \
      const float* p0 = xfb + ((tb.x >> 18) & 4095);                           \
      u32x4 q0, q1;                                                            \
      _Pragma("unroll") for (int d = 0; d < 4; ++d) {                          \
        unsigned int a0 = f2h(p0[(size_t)(2 * d)     << 12]);                  \
        unsigned int a1 = f2h(p0[(size_t)(2 * d + 1) << 12]);                  \
        q0[d] = a0 | (a1 << 16);                                               \
        unsigned int c0 = f2h(p0[((size_t)(2 * d)     << 12) + 1]);            \
        unsigned int c1 = f2h(p0[((size_t)(2 * d + 1) << 12) + 1]);            \
        q1[d] = c0 | (c1 << 16);                                               \
      }                                                                        \
      T0[S] = q0; T1[S] = q1;                                                  \
    }                                                                          \
    if (tb.y < 0) {   /* rare: bottom sample row outside window */             \
      const float* p1 = xfb + ((tb.y >> 18) & 4095);                           \
      u32x4 q0, q1;                                                            \
      _Pragma("unroll") for (int d = 0; d < 4; ++d) {                          \
        unsigned int a0 = f2h(p1[(size_t)(2 * d)     << 12]);                  \
        unsigned int a1 = f2h(p1[(size_t)(2 * d + 1) << 12]);                  \
        q0[d] = a0 | (a1 << 16);                                               \
        unsigned int c0 = f2h(p1[((size_t)(2 * d)     << 12) + 1]);            \
        unsigned int c1 = f2h(p1[((size_t)(2 * d + 1) << 12) + 1]);            \
        q1[d] = c0 | (c1 << 16);                                               \
      }                                                                        \
      B0[S] = q0; B1[S] = q1;                                                  \
    }                                                                          \
  }

#define INTERP(S, PG) {                                                        \
    const __half2 wtl = __half2half2(__low2half(h2_of((unsigned)tbc[PG].z)));  \
    const __half2 wtr = __half2half2(__high2half(h2_of((unsigned)tbc[PG].z))); \
    const __half2 wbl = __half2half2(__low2half(h2_of((unsigned)tbc[PG].w)));  \
    const __half2 wbr = __half2half2(__high2half(h2_of((unsigned)tbc[PG].w))); \
    u32x4 pk;                                                                  \
    _Pragma("unroll") for (int d = 0; d < 4; ++d) {                            \
      __half2 s = __hmul2(wtl, h2_of(T0[S][d]));                               \
      s = __hfma2(wtr, h2_of(T1[S][d]), s);                                    \
      s = __hfma2(wbl, h2_of(B0[S][d]), s);                                    \
      s = __hfma2(wbr, h2_of(B1[S][d]), s);                                    \
      pk[d] = u_of(s);                                                         \
    }                                                                          \
    f16x8 bfrag;                                                               \
    __builtin_memcpy(&bfrag, &pk, 16);                                         \
    _Pragma("unroll") for (int mt = 0; mt < 8; ++mt)                           \
      acc[PG][mt] = __builtin_amdgcn_mfma_f32_16x16x32_f16(A[mt], bfrag,       \
                                                           acc[PG][mt], 0, 0, 0); \
  }

  for (int tap = 0; tap < 9; ++tap) {
    // prefetch next tap's table entries (global, hidden under this tap's body)
    int4 tbn[4];
    if (tap < 8) {
#pragma unroll
      for (int pg = 0; pg < 4; ++pg)
        tbn[pg] = tabp[(tap + 1) * 64 + pg * 16];
    }

    // A-fragments: all 8 m-tiles (full Cout per wave), global L2-hot
    f16x8 A[8];
    const unsigned short* wp = wfb + (size_t)((ks * 9 + tap) * 8) * 512;
#pragma unroll
    for (int mt = 0; mt < 8; ++mt)
      A[mt] = *reinterpret_cast<const f16x8*>(wp + (size_t)mt * 512);

    // rolling 3-slot T/B window: addresses come straight from tbc registers
    u32x4 T0[3], T1[3], B0[3], B1[3];
    ISSUE(0, 0)
    ISSUE(1, 1)
    ISSUE(2, 2)
    INTERP(0, 0)
    ISSUE(0, 3)
    INTERP(1, 1)
    INTERP(2, 2)
    INTERP(0, 3)

#pragma unroll
    for (int pg = 0; pg < 4; ++pg) tbc[pg] = tbn[pg];
  }
#undef ISSUE
#undef INTERP

  // ---- epilogue 1: pairwise LDS tree-reduce (5 barriers, parallel writes) --
  // regB at float ofs 0 (rows at row*8448), regA at 17408 (rows at +row*8448).
  // C/D layout: wo = pg*16+ln, co = mt*16 + kg*4 + reg.
  float* sF = reinterpret_cast<float*>(sWin);
#define WR_LDS(BASE)                                                           \
  { _Pragma("unroll") for (int pg = 0; pg < 4; ++pg)                           \
    _Pragma("unroll") for (int mt = 0; mt < 8; ++mt)                           \
      *reinterpret_cast<f32x4*>(&sF[(BASE) + row * 8448 + (pg * 16 + ln) * 132 + mt * 16 + kg * 4]) = acc[pg][mt]; }
#define RD_LDS(BASE)                                                           \
  { _Pragma("unroll") for (int pg = 0; pg < 4; ++pg)                           \
    _Pragma("unroll") for (int mt = 0; mt < 8; ++mt) {                         \
      f32x4 v = *reinterpret_cast<const f32x4*>(&sF[(BASE) + row * 8448 + (pg * 16 + ln) * 132 + mt * 16 + kg * 4]); \
      acc[pg][mt] += v; } }

  __syncthreads();
  if (ks == 1) WR_LDS(17408)
  if (ks == 3) WR_LDS(0)
  __syncthreads();
  if (ks == 0) RD_LDS(17408)
  if (ks == 2) RD_LDS(0)
  __syncthreads();
  if (ks == 2) WR_LDS(17408)
  __syncthreads();
  if (ks == 0) RD_LDS(17408)
#undef WR_LDS
#undef RD_LDS

  // ---- epilogue 2: transpose via LDS [co][wo] (stride 68) -> dwordx4 stores
  // transpose region at float ofs row*8704 (max 17403 < 17408 = regA base).
  {
    const int b2 = row * 8704;
    if (ks == 0) {
#pragma unroll
      for (int pg = 0; pg < 4; ++pg)
#pragma unroll
        for (int mt = 0; mt < 8; ++mt)
#pragma unroll
          for (int rg = 0; rg < 4; ++rg)
            sF[b2 + (mt * 16 + kg * 4 + rg) * 68 + pg * 16 + ln] = acc[pg][mt][rg];
    }
    __syncthreads();
    if (ks == 0) {
      const int q4  = l & 15;       // wo quad: wo = q4*4..q4*4+3
      const int ch2 = l >> 4;       // co quarter
      float* ob = out + (((size_t)b * 128) * 64 + ho) * 64 + q4 * 4;
#pragma unroll
      for (int i = 0; i < 32; ++i) {
        int co = ch2 * 32 + i;
        f32x4 v = *reinterpret_cast<const f32x4*>(&sF[b2 + co * 68 + q4 * 4]);
        *reinterpret_cast<f32x4*>(ob + (size_t)co * 4096) = v;
      }
    }
  }
}

extern "C" void kernel_launch(void* const* d_in, const int* in_sizes, int n_in,
                              void* d_out, int out_size, void* d_ws, size_t ws_size,
                              hipStream_t stream) {
  (void)in_sizes; (void)n_in; (void)out_size; (void)ws_size;
  const float* x   = (const float*)d_in[0];
  const float* off = (const float*)d_in[1];
  const float* w   = (const float*)d_in[2];
  float* out = (float*)d_out;
  unsigned short* wf = (unsigned short*)d_ws;                    // 294912 B
  int4* tab = (int4*)((char*)d_ws + 294912);                     // 4718592 B

  prep_kernel<<<1224, 256, 0, stream>>>(w, off, wf, tab);
  deform_kernel<<<256, 512, 0, stream>>>(x, tab, wf, out);
}

// Round 5
// 96.663 us; speedup vs baseline: 1.3186x; 1.0304x over previous
//
#include <hip/hip_runtime.h>
#include <hip/hip_fp16.h>

typedef __attribute__((ext_vector_type(4))) float f32x4;
typedef __attribute__((ext_vector_type(8))) _Float16 f16x8;
typedef __attribute__((ext_vector_type(4))) unsigned int u32x4;

// float -> fp16 bits, round-nearest-even
__device__ __forceinline__ unsigned short f2h(float f) {
  __half h = __float2half_rn(f);
  unsigned short u;
  __builtin_memcpy(&u, &h, 2);
  return u;
}
// dword <-> __half2 helpers (ext_vector elements can't be addressed directly)
__device__ __forceinline__ __half2 h2_of(unsigned int u) {
  __half2 h;
  __builtin_memcpy(&h, &u, 4);
  return h;
}
__device__ __forceinline__ unsigned int u_of(__half2 h) {
  unsigned int u;
  __builtin_memcpy(&u, &h, 4);
  return u;
}

// ---------------------------------------------------------------------------
// Prep kernel (weights only, verified R14).
// Repack weight fp32 -> fp16 MFMA A-fragments:
//   wf[((ch*8 + mt)*64 + lane)*8 + j] = fp16(W[mt*16+(lane&15)]
//                                            [cc*32 + (lane>>4)*8 + j][tap])
// ch = cc*9 + tap (layouts verified R2-R12).
// ---------------------------------------------------------------------------
__global__ __launch_bounds__(256) void prep_kernel(const float* __restrict__ w,
                                                   unsigned short* __restrict__ wf) {
  int tid = blockIdx.x * 256 + threadIdx.x;   // 0..18431
  int l  = tid & 63;
  int mt = (tid >> 6) & 7;
  int ch = tid >> 9;                          // 0..35
  int cc = ch / 9, tap = ch - cc * 9;
  int co = mt * 16 + (l & 15);
  int cb = cc * 32 + (l >> 4) * 8;
  unsigned int r[8];
#pragma unroll
  for (int j = 0; j < 8; ++j)
    r[j] = f2h(w[(co * 128 + cb + j) * 9 + tap]);
  u32x4 pk;
  pk.x = r[0] | (r[1] << 16);
  pk.y = r[2] | (r[3] << 16);
  pk.z = r[4] | (r[5] << 16);
  pk.w = r[6] | (r[7] << 16);
  *reinterpret_cast<u32x4*>(wf + (size_t)tid * 8) = pk;
}

// ---------------------------------------------------------------------------
// Main kernel — measured-best configuration (R15 / session round 2, 96.5 µs).
// Restored verbatim after R16/R17 experiments regressed:
//  - table-to-global (R16/R17): prep 72->1224 blocks + un-hidden HBM round
//    trip for the 4.7 MB table = net +3 µs vs keeping sTab in LDS.
//  - direct scalar stores (R16): 11x HBM write amplification (64 B partial
//    lines at 16 KB stride thrash per-XCD L2) = +31 µs. Transpose epilogue
//    with 256 B-contiguous dwordx4 stores is the verified-correct fast form.
// Structure:
// (1) sTab[e] = int4 {packed laT|aX|oow, packed laB|aY|oow, top-wts, bot-wts}
//     -> ONE ds_read_b128 per (pg,tap), generated in-block (hidden under
//     window staging).
// (2) Table reads double-buffered across taps (tap t+1 prefetched during
//     tap t's body) — removes the leading ~120-cyc LDS latency of the
//     table->address->read chain at 2 waves/SIMD.
// (3) Rolling 3-slot T/B register window (issue pg0-2 / consume pg0 / issue
//     pg3 / consume pg1-3) keeps VGPRs under the 8-waves/CU cliff.
// (4) Fused fp32->fp16 window staging straight from x (NCHW, XCD-L2 resident
//     since b == XCD id): lane = p coalesced reads, ds_write_b128 stride 272
//     (2-way bank aliasing = free).
// (5) fp16 v_pk_fma interp -> mfma_f32_16x16x32_f16, 5-barrier pairwise tree
//     reduce, LDS-transpose dwordx4 stores.
// LDS: sWin 139264 B + sTab 18432 B = 157696 B (1 block/CU, 8 waves).
// Budget note: dur_us ≈ 2x44 µs harness workspace-poison fills (fixed) +
// prep (~1.5 µs) + deform (~7 µs, LDS-pipe floor ~6 µs).
// ---------------------------------------------------------------------------
__global__ __launch_bounds__(512, 1) void deform_kernel(const float* __restrict__ x,
                                                        const float* __restrict__ off,
                                                        const unsigned short* __restrict__ wf,
                                                        float* __restrict__ out) {
  // window: [r][p][c] bytes, p-stride 272 (16B pad), r-stride 64*272=17408
  __shared__ __align__(16) unsigned char sWin[8 * 17408];   // 139264 B
  __shared__ int4 sTab[1152];   // [row*576 + tap*64 + wo] addrs + fp16 wts

  const int tid = threadIdx.x;
  const int bid = blockIdx.x;
  const int b   = bid & 7;             // XCD-affine batch
  const int ho0 = (bid >> 3) * 2;      // first of the 2 output rows
  const int r0  = min(max(ho0 - 3, 0), 56);   // window base row

  // --- stage window rows r0..r0+7 from x (fp32 NCHW -> fp16 window) ---
  {
    const float* xb = x + ((size_t)b << 19) + ((size_t)r0 << 6);
#pragma unroll
    for (int it = 0; it < 16; ++it) {
      int idx = it * 512 + tid;        // [cg:4][r:3][p:6], 0..8191
      int p  = idx & 63;               // lane = p -> coalesced reads
      int r  = (idx >> 6) & 7;
      int cg = idx >> 9;
      const float* xp = xb + (((size_t)cg) << 15) + (r << 6) + p;
      unsigned int q[8];
#pragma unroll
      for (int j = 0; j < 8; ++j) q[j] = f2h(xp[(size_t)j << 12]);
      u32x4 pk;
      pk.x = q[0] | (q[1] << 16);
      pk.y = q[2] | (q[3] << 16);
      pk.z = q[4] | (q[5] << 16);
      pk.w = q[6] | (q[7] << 16);
      *reinterpret_cast<u32x4*>(&sWin[r * 17408 + p * 272 + cg * 16]) = pk;
    }
  }

  // --- precompute packed sampling addresses + separable folded fp16 weights -
  for (int r = tid; r < 1152; r += 512) {
    int row = (r >= 576) ? 1 : 0;
    int rr  = r - row * 576;
    int tap = rr >> 6, wo = rr & 63;
    int ho = ho0 + row;
    float dy = off[((b * 18 + 2 * tap)     * 64 + ho) * 64 + wo];
    float dx = off[((b * 18 + 2 * tap + 1) * 64 + ho) * 64 + wo];
    float py = (float)(ho + (tap / 3) - 1) + dy;
    float px = (float)(wo + (tap % 3) - 1) + dx;
    float fy = floorf(py), fx = floorf(px);
    int y0 = (int)fy, x0 = (int)fx;
    float wy = py - fy, wx = px - fx;
    float wt = (y0 >= 0 && y0 < 64) ? (1.f - wy) : 0.f;
    float wb = (y0 + 1 >= 0 && y0 + 1 < 64) ? wy : 0.f;
    int y0c = min(max(y0, 0), 63), y1c = min(max(y0 + 1, 0), 63);
    int bx; float wl, wr;
    if (x0 >= 0 && x0 <= 62)      { bx = x0; wl = 1.f - wx; wr = wx;       }
    else if (x0 == -1)            { bx = 0;  wl = wx;       wr = 0.f;      }
    else if (x0 == 63)            { bx = 62; wl = 0.f;      wr = 1.f - wx; }
    else                          { bx = 0;  wl = 0.f;      wr = 0.f;      }
    // packed addresses: laT/laB (18b) | global pos (12b) << 18 | oow << 31
    int aX = y0c * 64 + bx, aY = y1c * 64 + bx;
    int twr = y0c - r0, bwr = y1c - r0;
    int tin = ((unsigned)twr < 8u) ? 1 : 0;
    int bin = ((unsigned)bwr < 8u) ? 1 : 0;
    int laT0 = (tin ? twr : 0) * 17408 + bx * 272;
    int laB0 = (bin ? bwr : 0) * 17408 + bx * 272;
    int4 pw;
    pw.x = laT0 | (aX << 18) | (tin ? 0 : (int)0x80000000);
    pw.y = laB0 | (aY << 18) | (bin ? 0 : (int)0x80000000);
    pw.z = (int)u_of(__floats2half2_rn(wt * wl, wt * wr));
    pw.w = (int)u_of(__floats2half2_rn(wb * wl, wb * wr));
    sTab[r] = pw;
  }
  __syncthreads();

  const int l   = tid & 63;
  const int w   = tid >> 6;       // wave id 0..7
  const int ks  = w & 3;          // channel slab
  const int row = w >> 2;         // output row (ho0 + row)
  const int ln  = l & 15;
  const int kg  = l >> 4;         // k-group (8 consecutive channels)
  const int koff = ks * 64 + kg * 16;   // lane's channel byte offset in record
  const int ho  = ho0 + row;
  const int tbase = row * 576 + ln;

  // per-lane fp32 base for the rare out-of-window fallback: channels
  // ks*32+kg*8 .. +7, planes 4096 floats apart
  const float* xfb = x + ((size_t)b << 19) + (((size_t)(ks * 32 + kg * 8)) << 12);
  const unsigned short* wfb = wf + (size_t)l * 8;

  f32x4 acc[4][8] = {};   // [pos-group][m-tile] -> AGPRs

  // preload tap 0's table entries
  int4 tbc[4];
#pragma unroll
  for (int pg = 0; pg < 4; ++pg) tbc[pg] = sTab[tbase + pg * 16];

#define ISSUE(S, PG) {                                                         \
    const int4 tb = tbc[PG];                                                   \
    const int laT = (tb.x & 0x3FFFF) + koff;                                   \
    __builtin_memcpy(&T0[S], &sWin[laT],       16);                            \
    __builtin_memcpy(&T1[S], &sWin[laT + 272], 16);                            \
    const int laB = (tb.y & 0x3FFFF) + koff;                                   \
    __builtin_memcpy(&B0[S], &sWin[laB],       16);                            \
    __builtin_memcpy(&B1[S], &sWin[laB + 272], 16);                            \
    if (tb.x < 0) {   /* rare: top sample row outside window -> global fp32 */ \
      const float* p0 = xfb + ((tb.x >> 18) & 4095);                           \
      u32x4 q0, q1;                                                            \
      _Pragma("unroll") for (int d = 0; d < 4; ++d) {                          \
        unsigned int a0 = f2h(p0[(size_t)(2 * d)     << 12]);                  \
        unsigned int a1 = f2h(p0[(size_t)(2 * d + 1) << 12]);                  \
        q0[d] = a0 | (a1 << 16);                                               \
        unsigned int c0 = f2h(p0[((size_t)(2 * d)     << 12) + 1]);            \
        unsigned int c1 = f2h(p0[((size_t)(2 * d + 1) << 12) + 1]);            \
        q1[d] = c0 | (c1 << 16);                                               \
      }                                                                        \
      T0[S] = q0; T1[S] = q1;                                                  \
    }                                                                          \
    if (tb.y < 0) {   /* rare: bottom sample row outside window */             \
      const float* p1 = xfb + ((tb.y >> 18) & 4095);                           \
      u32x4 q0, q1;                                                            \
      _Pragma("unroll") for (int d = 0; d < 4; ++d) {                          \
        unsigned int a0 = f2h(p1[(size_t)(2 * d)     << 12]);                  \
        unsigned int a1 = f2h(p1[(size_t)(2 * d + 1) << 12]);                  \
        q0[d] = a0 | (a1 << 16);                                               \
        unsigned int c0 = f2h(p1[((size_t)(2 * d)     << 12) + 1]);            \
        unsigned int c1 = f2h(p1[((size_t)(2 * d + 1) << 12) + 1]);            \
        q1[d] = c0 | (c1 << 16);                                               \
      }                                                                        \
      B0[S] = q0; B1[S] = q1;                                                  \
    }                                                                          \
  }

#define INTERP(S, PG) {                                                        \
    const __half2 wtl = __half2half2(__low2half(h2_of((unsigned)tbc[PG].z)));  \
    const __half2 wtr = __half2half2(__high2half(h2_of((unsigned)tbc[PG].z))); \
    const __half2 wbl = __half2half2(__low2half(h2_of((unsigned)tbc[PG].w)));  \
    const __half2 wbr = __half2half2(__high2half(h2_of((unsigned)tbc[PG].w))); \
    u32x4 pk;                                                                  \
    _Pragma("unroll") for (int d = 0; d < 4; ++d) {                            \
      __half2 s = __hmul2(wtl, h2_of(T0[S][d]));                               \
      s = __hfma2(wtr, h2_of(T1[S][d]), s);                                    \
      s = __hfma2(wbl, h2_of(B0[S][d]), s);                                    \
      s = __hfma2(wbr, h2_of(B1[S][d]), s);                                    \
      pk[d] = u_of(s);                                                         \
    }                                                                          \
    f16x8 bfrag;                                                               \
    __builtin_memcpy(&bfrag, &pk, 16);                                         \
    _Pragma("unroll") for (int mt = 0; mt < 8; ++mt)                           \
      acc[PG][mt] = __builtin_amdgcn_mfma_f32_16x16x32_f16(A[mt], bfrag,       \
                                                           acc[PG][mt], 0, 0, 0); \
  }

  for (int tap = 0; tap < 9; ++tap) {
    // prefetch next tap's table entries (hidden under this tap's body)
    int4 tbn[4];
    if (tap < 8) {
#pragma unroll
      for (int pg = 0; pg < 4; ++pg)
        tbn[pg] = sTab[tbase + (tap + 1) * 64 + pg * 16];
    }

    // A-fragments: all 8 m-tiles (full Cout per wave), global L2-hot
    f16x8 A[8];
    const unsigned short* wp = wfb + (size_t)((ks * 9 + tap) * 8) * 512;
#pragma unroll
    for (int mt = 0; mt < 8; ++mt)
      A[mt] = *reinterpret_cast<const f16x8*>(wp + (size_t)mt * 512);

    // rolling 3-slot T/B window: addresses come straight from tbc registers
    u32x4 T0[3], T1[3], B0[3], B1[3];
    ISSUE(0, 0)
    ISSUE(1, 1)
    ISSUE(2, 2)
    INTERP(0, 0)
    ISSUE(0, 3)
    INTERP(1, 1)
    INTERP(2, 2)
    INTERP(0, 3)

#pragma unroll
    for (int pg = 0; pg < 4; ++pg) tbc[pg] = tbn[pg];
  }
#undef ISSUE
#undef INTERP

  // ---- epilogue 1: pairwise LDS tree-reduce (5 barriers, parallel writes) --
  // regB at float ofs 0 (rows at row*8448), regA at 17408 (rows at +row*8448).
  // C/D layout: wo = pg*16+ln, co = mt*16 + kg*4 + reg.
  float* sF = reinterpret_cast<float*>(sWin);
#define WR_LDS(BASE)                                                           \
  { _Pragma("unroll") for (int pg = 0; pg < 4; ++pg)                           \
    _Pragma("unroll") for (int mt = 0; mt < 8; ++mt)                           \
      *reinterpret_cast<f32x4*>(&sF[(BASE) + row * 8448 + (pg * 16 + ln) * 132 + mt * 16 + kg * 4]) = acc[pg][mt]; }
#define RD_LDS(BASE)                                                           \
  { _Pragma("unroll") for (int pg = 0; pg < 4; ++pg)                           \
    _Pragma("unroll") for (int mt = 0; mt < 8; ++mt) {                         \
      f32x4 v = *reinterpret_cast<const f32x4*>(&sF[(BASE) + row * 8448 + (pg * 16 + ln) * 132 + mt * 16 + kg * 4]); \
      acc[pg][mt] += v; } }

  __syncthreads();
  if (ks == 1) WR_LDS(17408)
  if (ks == 3) WR_LDS(0)
  __syncthreads();
  if (ks == 0) RD_LDS(17408)
  if (ks == 2) RD_LDS(0)
  __syncthreads();
  if (ks == 2) WR_LDS(17408)
  __syncthreads();
  if (ks == 0) RD_LDS(17408)
#undef WR_LDS
#undef RD_LDS

  // ---- epilogue 2: transpose via LDS [co][wo] (stride 68) -> dwordx4 stores
  // transpose region at float ofs row*8704 (max 17403 < 17408 = regA base).
  {
    const int b2 = row * 8704;
    if (ks == 0) {
#pragma unroll
      for (int pg = 0; pg < 4; ++pg)
#pragma unroll
        for (int mt = 0; mt < 8; ++mt)
#pragma unroll
          for (int rg = 0; rg < 4; ++rg)
            sF[b2 + (mt * 16 + kg * 4 + rg) * 68 + pg * 16 + ln] = acc[pg][mt][rg];
    }
    __syncthreads();
    if (ks == 0) {
      const int q4  = l & 15;       // wo quad: wo = q4*4..q4*4+3
      const int ch2 = l >> 4;       // co quarter
      float* ob = out + (((size_t)b * 128) * 64 + ho) * 64 + q4 * 4;
#pragma unroll
      for (int i = 0; i < 32; ++i) {
        int co = ch2 * 32 + i;
        f32x4 v = *reinterpret_cast<const f32x4*>(&sF[b2 + co * 68 + q4 * 4]);
        *reinterpret_cast<f32x4*>(ob + (size_t)co * 4096) = v;
      }
    }
  }
}

extern "C" void kernel_launch(void* const* d_in, const int* in_sizes, int n_in,
                              void* d_out, int out_size, void* d_ws, size_t ws_size,
                              hipStream_t stream) {
  (void)in_sizes; (void)n_in; (void)out_size; (void)ws_size;
  const float* x   = (const float*)d_in[0];
  const float* off = (const float*)d_in[1];
  const float* w   = (const float*)d_in[2];
  float* out = (float*)d_out;
  unsigned short* wf = (unsigned short*)d_ws;   // 294912 B

  prep_kernel<<<72, 256, 0, stream>>>(w, wf);
  deform_kernel<<<256, 512, 0, stream>>>(x, off, wf, out);
}